// Round 6
// baseline (456.226 us; speedup 1.0000x reference)
//
#include <hip/hip_runtime.h>
#include <cmath>
#include <complex>
#include <cstring>
#include <algorithm>

#define DIM_IN  288
#define DIM_SHD 9
#define NB      10
#define NH      16
#define EPB     32
#define BLOCK   512
#define NINSTR  11
#define XSTR    292
#define ZSTR    161
#define W2B_ELEMS (NINSTR * 32 * 32 * 32)   // [ins][u][w][t0..31], t>=16 zero

// LDS pool layout (floats):
//   s_xo   : [0, 9344)            32*292  x staging; reused for out gather
//   s_z    : [9344, 19648)        2*32*161 z double buffer
//   s_sh   : [19648, 20032)       32*12
//   s_basis: alias s_z[1][0..319]           (dead before z_phase<1>)
//   s_hb   : alias s_z[1][320..832) ushort  (dead before z_phase<1>)
#define OFF_XO 0
#define OFF_Z  9344
#define OFF_SH 19648
#define POOLSZ 20032

typedef __attribute__((ext_vector_type(8))) short  short8b;
typedef __attribute__((ext_vector_type(4))) float  f32x4;

__device__ float g_C[NINSTR][125];

__device__ __forceinline__ unsigned short f2bf(float f) {
  unsigned int u = __float_as_uint(f);
  unsigned int r = (u + 0x7fffu + ((u >> 16) & 1u)) >> 16;   // RNE
  return (unsigned short)r;
}

// W2 -> bf16, [ins][u][w][t] with t padded 16->32 with zeros
__global__ __launch_bounds__(256) void prep_w2(const float* __restrict__ W2,
                                               unsigned short* __restrict__ W2b) {
  int gid = blockIdx.x * 256 + threadIdx.x;
  if (gid < W2B_ELEMS) {
    int c = gid >> 5, t = gid & 31;          // c = ins*1024 + u*32 + w
    W2b[gid] = (t < 16) ? f2bf(W2[(size_t)t * 11264 + c]) : (unsigned short)0;
  }
}

// ---- z-phase: 32 edges x 32 u over 512 threads, LDS->LDS ----
template<int INS,int D1,int D2,int D3,int OFF1,int OFF2>
__device__ __forceinline__ void z_phase(
    int tid, const float* __restrict__ s_x,
    const float* __restrict__ s_sh, float* __restrict__ zdst)
{
  const float* __restrict__ Cp = g_C[INS];
  #pragma unroll
  for (int s = 0; s < 2; ++s) {
    int id = tid + s * BLOCK;
    int e = id >> 5, u = id & 31;
    const float* xe = s_x + e * XSTR + OFF1 + u * D1;
    float zk[D3];
    #pragma unroll
    for (int k = 0; k < D3; ++k) zk[k] = 0.f;
    #pragma unroll
    for (int i = 0; i < D1; ++i) {
      float xv = xe[i];
      #pragma unroll
      for (int j = 0; j < D2; ++j) {
        float pr = xv * s_sh[e * 12 + OFF2 + j];
        #pragma unroll
        for (int k = 0; k < D3; ++k)
          zk[k] = fmaf(Cp[(i * D2 + j) * D3 + k], pr, zk[k]);
      }
    }
    #pragma unroll
    for (int k = 0; k < D3; ++k) zdst[e * ZSTR + k * 32 + u] = zk[k];
  }
}

// ---- MFMA weight-gen + u-contraction, 3-deep prefetch ----
template<int INS,int D3,int SB>
__device__ __forceinline__ void contract(
    int ls, int lq, int a_wt, int b_uh, int my_e,
    const unsigned short* __restrict__ W2b, const float* __restrict__ b2,
    const float* __restrict__ zbuf, short8b hB, float (&acc)[4][9])
{
  const unsigned short* Ap =
      W2b + ((size_t)(INS * 32 + b_uh * 16) * 32 + a_wt * 16 + ls) * 32 + lq * 8;
  const float* bbase = b2 + INS * 1024 + b_uh * 512 + a_wt * 16 + lq * 4;
  const float* zb = zbuf + my_e * ZSTR + b_uh * 16;

  short8b Ra = *(const short8b*)(Ap);
  short8b Rb = *(const short8b*)(Ap + 1024);
  short8b Rc = *(const short8b*)(Ap + 2048);
  float4  Ba = *(const float4*)(bbase);
  float4  Bb = *(const float4*)(bbase + 32);
  float4  Bc = *(const float4*)(bbase + 64);

  f32x4 c0 = {Ba.x, Ba.y, Ba.z, Ba.w};
  f32x4 w_cur = __builtin_amdgcn_mfma_f32_16x16x32_bf16(Ra, hB, c0, 0, 0, 0);

  #pragma unroll
  for (int i = 0; i < 16; ++i) {
    f32x4 w_next;
    if (i < 15) {
      f32x4 cn = {Bb.x, Bb.y, Bb.z, Bb.w};
      w_next = __builtin_amdgcn_mfma_f32_16x16x32_bf16(Rb, hB, cn, 0, 0, 0);
      Rb = Rc; Bb = Bc;
      if (i + 3 < 16) {
        Rc = *(const short8b*)(Ap + (size_t)(i + 3) * 1024);
        Bc = *(const float4*)(bbase + (i + 3) * 32);
      }
    }
    #pragma unroll
    for (int k = 0; k < D3; ++k) {
      float zv = zb[k * 32 + i];          // 4-lane same-address broadcast
      acc[0][SB + k] = fmaf(w_cur[0], zv, acc[0][SB + k]);
      acc[1][SB + k] = fmaf(w_cur[1], zv, acc[1][SB + k]);
      acc[2][SB + k] = fmaf(w_cur[2], zv, acc[2][SB + k]);
      acc[3][SB + k] = fmaf(w_cur[3], zv, acc[3][SB + k]);
    }
    if (i < 15) w_cur = w_next;
  }
}

__global__ __launch_bounds__(BLOCK, 4) void conv_kernel(
    const float* __restrict__ xg, const float* __restrict__ shg,
    const float* __restrict__ dist, const float* __restrict__ freq,
    const float* __restrict__ W1, const float* __restrict__ b1,
    const unsigned short* __restrict__ W2b, const float* __restrict__ b2,
    float* __restrict__ out)
{
  __shared__ float s_pool[POOLSZ];        // 80128 B -> 2 blocks/CU
  float* s_xo = s_pool + OFF_XO;
  float* s_z0 = s_pool + OFF_Z;
  float* s_z1 = s_pool + OFF_Z + EPB * ZSTR;
  float* s_sh = s_pool + OFF_SH;
  float* s_basis = s_z1;                               // 320 floats, aliased
  unsigned short* s_hb = (unsigned short*)(s_z1 + 320); // 1024 shorts, aliased

  const int tid = threadIdx.x;
  const int e0 = blockIdx.x * EPB;
  const int l  = tid & 63;
  const int ls = l & 15;          // e-col (B/C cols) & w-row selector (A rows)
  const int lq = l >> 4;          // 0..3 k-slice / output reg quad
  const int wid = tid >> 6;       // 0..7
  const int et  = wid >> 2;       // e-tile 0/1
  const int a_wt = (wid >> 1) & 1;// w-tile 0/1
  const int b_uh = wid & 1;       // u-half 0/1
  const int my_e = et * 16 + ls;

  // ---- region A: stage x (coalesced), sh, radial basis ----
  for (int i4 = tid; i4 < EPB * 72; i4 += BLOCK) {
    int e = i4 / 72, r = i4 - e * 72;
    *(float4*)(s_xo + e * XSTR + r * 4) =
        *(const float4*)(xg + (size_t)(e0 + e) * DIM_IN + r * 4);
  }
  if (tid < EPB * DIM_SHD) {
    int e = tid / DIM_SHD, c = tid - e * DIM_SHD;
    s_sh[e * 12 + c] = shg[(size_t)(e0 + e) * DIM_SHD + c];
  }
  {
    int bi = tid - BLOCK + EPB * NB;       // last 320 threads do basis
    if (bi >= 0) {
      int e = bi / NB, n = bi - (bi / NB) * NB;
      float d  = dist[e0 + e];
      float xv = d * 0.25f;
      float x2 = xv * xv, x4 = x2 * x2, x5 = x4 * xv;
      float env = 1.0f / xv + x5 * fmaf(xv, fmaf(xv, -21.0f, 48.0f), -28.0f);
      env = (xv < 1.0f) ? env : 0.0f;
      s_basis[e * NB + n] = env * sinf(freq[n] * xv);
    }
  }
  __syncthreads();

  // ---- region B: radial MLP hidden layer (512 tasks) + z for instr 0 ----
  {
    int e = tid >> 4, t = tid & 15;
    float v = b1[t];
    #pragma unroll
    for (int n = 0; n < NB; ++n) v = fmaf(s_basis[e * NB + n], W1[n * NH + t], v);
    v = v / (1.0f + expf(-v));          // silu
    s_hb[e * 32 + t] = f2bf(v);
    s_hb[e * 32 + t + 16] = 0;
  }
  z_phase< 0, 1, 1, 1,   0, 0>(tid, s_xo, s_sh, s_z0);
  __syncthreads();

  short8b hB = *(const short8b*)(s_hb + my_e * 32 + lq * 8);
  __syncthreads();   // protect aliased s_basis/s_hb before z_phase<1> overwrite

  float acc[4][9];
  #pragma unroll
  for (int r = 0; r < 4; ++r)
    #pragma unroll
    for (int a = 0; a < 9; ++a) acc[r][a] = 0.f;

  // ---- pipelined main: z(i+1) || contract(i), one barrier each ----
  z_phase< 1, 1, 3, 3,   0, 1>(tid, s_xo, s_sh, s_z1);
  contract< 0, 1, 0>(ls, lq, a_wt, b_uh, my_e, W2b, b2, s_z0, hB, acc);
  __syncthreads();
  z_phase< 2, 1, 5, 5,   0, 4>(tid, s_xo, s_sh, s_z0);
  contract< 1, 3, 1>(ls, lq, a_wt, b_uh, my_e, W2b, b2, s_z1, hB, acc);
  __syncthreads();
  z_phase< 3, 3, 1, 3,  32, 0>(tid, s_xo, s_sh, s_z1);
  contract< 2, 5, 4>(ls, lq, a_wt, b_uh, my_e, W2b, b2, s_z0, hB, acc);
  __syncthreads();
  z_phase< 4, 3, 3, 1,  32, 1>(tid, s_xo, s_sh, s_z0);
  contract< 3, 3, 1>(ls, lq, a_wt, b_uh, my_e, W2b, b2, s_z1, hB, acc);
  __syncthreads();
  z_phase< 5, 3, 3, 5,  32, 1>(tid, s_xo, s_sh, s_z1);
  contract< 4, 1, 0>(ls, lq, a_wt, b_uh, my_e, W2b, b2, s_z0, hB, acc);
  __syncthreads();
  z_phase< 6, 3, 5, 3,  32, 4>(tid, s_xo, s_sh, s_z0);
  contract< 5, 5, 4>(ls, lq, a_wt, b_uh, my_e, W2b, b2, s_z1, hB, acc);
  __syncthreads();
  z_phase< 7, 5, 1, 5, 128, 0>(tid, s_xo, s_sh, s_z1);
  contract< 6, 3, 1>(ls, lq, a_wt, b_uh, my_e, W2b, b2, s_z0, hB, acc);
  __syncthreads();
  z_phase< 8, 5, 3, 3, 128, 1>(tid, s_xo, s_sh, s_z0);
  contract< 7, 5, 4>(ls, lq, a_wt, b_uh, my_e, W2b, b2, s_z1, hB, acc);
  __syncthreads();
  z_phase< 9, 5, 5, 1, 128, 4>(tid, s_xo, s_sh, s_z1);
  contract< 8, 3, 1>(ls, lq, a_wt, b_uh, my_e, W2b, b2, s_z0, hB, acc);
  __syncthreads();
  z_phase<10, 5, 5, 5, 128, 4>(tid, s_xo, s_sh, s_z0);
  contract< 9, 1, 0>(ls, lq, a_wt, b_uh, my_e, W2b, b2, s_z1, hB, acc);
  __syncthreads();
  contract<10, 5, 4>(ls, lq, a_wt, b_uh, my_e, W2b, b2, s_z0, hB, acc);

  // ---- cross-wave (u-half) reduction into s_xo (x reads all done) ----
  __syncthreads();
  if (b_uh == 1) {
    float* row = s_xo + my_e * XSTR;
    #pragma unroll
    for (int r = 0; r < 4; ++r) {
      int w = a_wt * 16 + lq * 4 + r;
      row[w] = acc[r][0];
      #pragma unroll
      for (int k = 0; k < 3; ++k) row[32 + w * 3 + k] = acc[r][1 + k];
      #pragma unroll
      for (int k = 0; k < 5; ++k) row[128 + w * 5 + k] = acc[r][4 + k];
    }
  }
  __syncthreads();
  if (b_uh == 0) {
    float* row = s_xo + my_e * XSTR;
    #pragma unroll
    for (int r = 0; r < 4; ++r) {
      int w = a_wt * 16 + lq * 4 + r;
      row[w] += acc[r][0];
      #pragma unroll
      for (int k = 0; k < 3; ++k) row[32 + w * 3 + k] += acc[r][1 + k];
      #pragma unroll
      for (int k = 0; k < 5; ++k) row[128 + w * 5 + k] += acc[r][4 + k];
    }
  }
  __syncthreads();
  // coalesced store: 32 rows x 288 = 2304 float4
  for (int i4 = tid; i4 < EPB * 72; i4 += BLOCK) {
    int e = i4 / 72, r = i4 - e * 72;
    float4 v = *(const float4*)(s_xo + e * XSTR + r * 4);
    *(float4*)(out + (size_t)(e0 + e) * DIM_IN + r * 4) = v;
  }
}

// ===================== host-side Wigner-3j (mirrors reference) =====================
typedef std::complex<double> cd;

static double factd(int n) { double r = 1; for (int i = 2; i <= n; ++i) r *= i; return r; }

static double su2_cg(int j1, int j2, int j3, int m1, int m2, int m3) {
  if (m3 != m1 + m2) return 0.0;
  int vmin = std::max(std::max(-j1 + j2 + m3, -j1 + m1), 0);
  int vmax = std::min(std::min(j2 + j3 + m1, j3 - j1 + j2), j3 + m3);
  if (vmax < vmin) return 0.0;
  double c = std::sqrt(
      factd(2*j3+1) * factd(j3+j1-j2) * factd(j3-j1+j2) * factd(j1+j2-j3) / factd(j1+j2+j3+1)
      * factd(j3+m3) * factd(j3-m3)
      / (factd(j1+m1) * factd(j1-m1) * factd(j2+m2) * factd(j2-m2)));
  double s = 0.0;
  for (int v = vmin; v <= vmax; ++v) {
    double sg = ((v + j2 + m2) & 1) ? -1.0 : 1.0;
    s += sg * factd(j2+j3+m1-v) * factd(j1-m1+v)
         / (factd(v) * factd(j3-j1+j2-v) * factd(j3+m3-v) * factd(v+j1-j2-m3));
  }
  return c * s;
}

static void qmat(int l, cd q[5][5]) {
  for (int a = 0; a < 5; ++a) for (int b = 0; b < 5; ++b) q[a][b] = cd(0, 0);
  const double s = 1.0 / std::sqrt(2.0);
  for (int m = -l; m < 0; ++m) {
    q[l + m][l - m] = cd(s, 0);
    q[l + m][l + m] = cd(0, -s);
  }
  q[l][l] = cd(1, 0);
  for (int m = 1; m <= l; ++m) {
    double sg = (m & 1) ? -1.0 : 1.0;
    q[l + m][l + m] = cd(sg * s, 0);
    q[l + m][l - m] = cd(0, sg * s);
  }
  cd ph = (l == 0) ? cd(1, 0) : (l == 1) ? cd(0, -1) : cd(-1, 0);  // (-i)^l
  for (int a = 0; a < 5; ++a) for (int b = 0; b < 5; ++b) q[a][b] *= ph;
}

static void wigner3j(int l1, int l2, int l3, double C[5][5][5]) {
  int d1 = 2*l1+1, d2 = 2*l2+1, d3 = 2*l3+1;
  cd q1[5][5], q2[5][5], q3[5][5];
  qmat(l1, q1); qmat(l2, q2); qmat(l3, q3);
  double norm2 = 0;
  for (int j = 0; j < d1; ++j)
    for (int l = 0; l < d2; ++l)
      for (int n = 0; n < d3; ++n) {
        cd sum(0, 0);
        for (int i = 0; i < d1; ++i)
          for (int k = 0; k < d2; ++k)
            for (int m = 0; m < d3; ++m) {
              double cg = su2_cg(l1, l2, l3, i - l1, k - l2, m - l3);
              if (cg != 0.0) sum += q1[i][j] * q2[k][l] * std::conj(q3[m][n]) * cg;
            }
        C[j][l][n] = sum.real();
        norm2 += C[j][l][n] * C[j][l][n];
      }
  double nrm = std::sqrt(norm2);
  if (nrm > 0)
    for (int j = 0; j < d1; ++j)
      for (int l = 0; l < d2; ++l)
        for (int n = 0; n < d3; ++n) C[j][l][n] /= nrm;
}

static void build_C_host(float C_out[NINSTR][125]) {
  const int L1[NINSTR] = {0,0,0,1,1,1,1,2,2,2,2};
  const int L2[NINSTR] = {0,1,2,0,1,1,2,0,1,2,2};
  const int L3[NINSTR] = {0,1,2,1,0,2,1,2,1,0,2};
  std::memset(C_out, 0, sizeof(float) * NINSTR * 125);
  for (int ins = 0; ins < NINSTR; ++ins) {
    int l1 = L1[ins], l2 = L2[ins], l3 = L3[ins];
    int d1 = 2*l1+1, d2 = 2*l2+1, d3 = 2*l3+1;
    double C[5][5][5];
    wigner3j(l1, l2, l3, C);
    double fan = (l3 == 0) ? 96.0 : 128.0;
    double pw = std::sqrt((2*l3+1) / fan);
    for (int i = 0; i < d1; ++i)
      for (int j = 0; j < d2; ++j)
        for (int k = 0; k < d3; ++k)
          C_out[ins][(i * d2 + j) * d3 + k] = (float)(pw * C[i][j][k]);
  }
}

extern "C" void kernel_launch(void* const* d_in, const int* in_sizes, int n_in,
                              void* d_out, int out_size, void* d_ws, size_t ws_size,
                              hipStream_t stream) {
  static float hC[NINSTR][125];
  build_C_host(hC);
  void* dC = nullptr;
  hipGetSymbolAddress(&dC, HIP_SYMBOL(g_C));
  hipMemcpyAsync(dC, hC, sizeof(hC), hipMemcpyHostToDevice, stream);

  const float* xg   = (const float*)d_in[0];
  const float* shg  = (const float*)d_in[1];
  const float* dist = (const float*)d_in[2];
  const float* freq = (const float*)d_in[3];
  const float* W1   = (const float*)d_in[4];
  const float* b1   = (const float*)d_in[5];
  const float* W2   = (const float*)d_in[6];
  const float* b2   = (const float*)d_in[7];
  float* out = (float*)d_out;
  unsigned short* W2b = (unsigned short*)d_ws;    // 720896 bytes

  prep_w2<<<(W2B_ELEMS + 255) / 256, 256, 0, stream>>>(W2, W2b);

  int E = in_sizes[2];            // 16384
  int blocks = E / EPB;           // 512
  conv_kernel<<<blocks, BLOCK, 0, stream>>>(xg, shg, dist, freq, W1, b1, W2b, b2, out);
}

// Round 7
// 109.704 us; speedup vs baseline: 4.1587x; 4.1587x over previous
//
#include <hip/hip_runtime.h>
#include <cmath>
#include <complex>
#include <cstring>
#include <algorithm>

#define DIM_IN  288
#define DIM_SHD 9
#define NB      10
#define NH      16
#define EPB     32
#define BLOCK   512
#define NINSTR  11
#define XSTR    292
#define ZSTR    161
#define W2B_ELEMS (NINSTR * 32 * 32 * 32)   // [ins][u][w][t0..31], t>=16 zero

// LDS pool layout (floats):
//   s_xo   : [0, 9344)            32*292  x staging; reused for out gather
//   s_z    : [9344, 19648)        2*32*161 z double buffer
//   s_sh   : [19648, 20032)       32*12
//   s_basis: alias s_z[1][0..319)           (dead before z_phase<1>)
//   s_hb   : alias s_z[1][320..832) ushort  (dead before z_phase<1>)
#define OFF_XO 0
#define OFF_Z  9344
#define OFF_SH 19648
#define POOLSZ 20032

typedef __attribute__((ext_vector_type(8))) short  short8b;
typedef __attribute__((ext_vector_type(4))) float  f32x4;

__device__ float g_C[NINSTR][125];

__device__ __forceinline__ unsigned short f2bf(float f) {
  unsigned int u = __float_as_uint(f);
  unsigned int r = (u + 0x7fffu + ((u >> 16) & 1u)) >> 16;   // RNE
  return (unsigned short)r;
}

// W2 -> bf16, [ins][u][w][t] with t padded 16->32 with zeros
__global__ __launch_bounds__(256) void prep_w2(const float* __restrict__ W2,
                                               unsigned short* __restrict__ W2b) {
  int gid = blockIdx.x * 256 + threadIdx.x;
  if (gid < W2B_ELEMS) {
    int c = gid >> 5, t = gid & 31;          // c = ins*1024 + u*32 + w
    W2b[gid] = (t < 16) ? f2bf(W2[(size_t)t * 11264 + c]) : (unsigned short)0;
  }
}

// ---- z-phase: 32 edges x 32 u over 512 threads, LDS->LDS ----
template<int INS,int D1,int D2,int D3,int OFF1,int OFF2>
__device__ __forceinline__ void z_phase(
    int tid, const float* __restrict__ s_x,
    const float* __restrict__ s_sh, float* __restrict__ zdst)
{
  const float* __restrict__ Cp = g_C[INS];
  #pragma unroll
  for (int s = 0; s < 2; ++s) {
    int id = tid + s * BLOCK;
    int e = id >> 5, u = id & 31;
    const float* xe = s_x + e * XSTR + OFF1 + u * D1;
    float zk[D3];
    #pragma unroll
    for (int k = 0; k < D3; ++k) zk[k] = 0.f;
    #pragma unroll
    for (int i = 0; i < D1; ++i) {
      float xv = xe[i];
      #pragma unroll
      for (int j = 0; j < D2; ++j) {
        float pr = xv * s_sh[e * 12 + OFF2 + j];
        #pragma unroll
        for (int k = 0; k < D3; ++k)
          zk[k] = fmaf(Cp[(i * D2 + j) * D3 + k], pr, zk[k]);
      }
    }
    #pragma unroll
    for (int k = 0; k < D3; ++k) zdst[e * ZSTR + k * 32 + u] = zk[k];
  }
}

// ---- MFMA weight-gen + u-contraction, 3-deep prefetch ----
template<int INS,int D3,int SB>
__device__ __forceinline__ void contract(
    int ls, int lq, int a_wt, int b_uh, int my_e,
    const unsigned short* __restrict__ W2b, const float* __restrict__ b2,
    const float* __restrict__ zbuf, short8b hB, float (&acc)[4][9])
{
  const unsigned short* Ap =
      W2b + ((size_t)(INS * 32 + b_uh * 16) * 32 + a_wt * 16 + ls) * 32 + lq * 8;
  const float* bbase = b2 + INS * 1024 + b_uh * 512 + a_wt * 16 + lq * 4;
  const float* zb = zbuf + my_e * ZSTR + b_uh * 16;

  short8b Ra = *(const short8b*)(Ap);
  short8b Rb = *(const short8b*)(Ap + 1024);
  short8b Rc = *(const short8b*)(Ap + 2048);
  float4  Ba = *(const float4*)(bbase);
  float4  Bb = *(const float4*)(bbase + 32);
  float4  Bc = *(const float4*)(bbase + 64);

  f32x4 c0 = {Ba.x, Ba.y, Ba.z, Ba.w};
  f32x4 w_cur = __builtin_amdgcn_mfma_f32_16x16x32_bf16(Ra, hB, c0, 0, 0, 0);

  #pragma unroll
  for (int i = 0; i < 16; ++i) {
    f32x4 w_next;
    if (i < 15) {
      f32x4 cn = {Bb.x, Bb.y, Bb.z, Bb.w};
      w_next = __builtin_amdgcn_mfma_f32_16x16x32_bf16(Rb, hB, cn, 0, 0, 0);
      Rb = Rc; Bb = Bc;
      if (i + 3 < 16) {
        Rc = *(const short8b*)(Ap + (size_t)(i + 3) * 1024);
        Bc = *(const float4*)(bbase + (i + 3) * 32);
      }
    }
    #pragma unroll
    for (int k = 0; k < D3; ++k) {
      float zv = zb[k * 32 + i];          // 4-lane same-address broadcast
      acc[0][SB + k] = fmaf(w_cur[0], zv, acc[0][SB + k]);
      acc[1][SB + k] = fmaf(w_cur[1], zv, acc[1][SB + k]);
      acc[2][SB + k] = fmaf(w_cur[2], zv, acc[2][SB + k]);
      acc[3][SB + k] = fmaf(w_cur[3], zv, acc[3][SB + k]);
    }
    if (i < 15) w_cur = w_next;
  }
}

// NOTE (journal): on this hipcc the 2nd __launch_bounds__ arg behaves as
// CUDA's min-BLOCKS-per-CU: (512,4) forced VGPR=64 (32-wave target) and
// spilled catastrophically (r6: FETCH 473MB). (512,2) => 16 waves/CU,
// VGPR cap 128 — matches this kernel's natural register footprint (r5).
__global__ __launch_bounds__(BLOCK, 2) void conv_kernel(
    const float* __restrict__ xg, const float* __restrict__ shg,
    const float* __restrict__ dist, const float* __restrict__ freq,
    const float* __restrict__ W1, const float* __restrict__ b1,
    const unsigned short* __restrict__ W2b, const float* __restrict__ b2,
    float* __restrict__ out)
{
  __shared__ float s_pool[POOLSZ];        // 80128 B -> 2 blocks/CU
  float* s_xo = s_pool + OFF_XO;
  float* s_z0 = s_pool + OFF_Z;
  float* s_z1 = s_pool + OFF_Z + EPB * ZSTR;
  float* s_sh = s_pool + OFF_SH;
  float* s_basis = s_z1;                               // 320 floats, aliased
  unsigned short* s_hb = (unsigned short*)(s_z1 + 320); // 1024 shorts, aliased

  const int tid = threadIdx.x;
  const int e0 = blockIdx.x * EPB;
  const int l  = tid & 63;
  const int ls = l & 15;          // e-col (B/C cols) & w-row selector (A rows)
  const int lq = l >> 4;          // 0..3 k-slice / output reg quad
  const int wid = tid >> 6;       // 0..7
  const int et  = wid >> 2;       // e-tile 0/1
  const int a_wt = (wid >> 1) & 1;// w-tile 0/1
  const int b_uh = wid & 1;       // u-half 0/1
  const int my_e = et * 16 + ls;

  // ---- region A: stage x (coalesced), sh, radial basis ----
  for (int i4 = tid; i4 < EPB * 72; i4 += BLOCK) {
    int e = i4 / 72, r = i4 - e * 72;
    *(float4*)(s_xo + e * XSTR + r * 4) =
        *(const float4*)(xg + (size_t)(e0 + e) * DIM_IN + r * 4);
  }
  if (tid < EPB * DIM_SHD) {
    int e = tid / DIM_SHD, c = tid - e * DIM_SHD;
    s_sh[e * 12 + c] = shg[(size_t)(e0 + e) * DIM_SHD + c];
  }
  {
    int bi = tid - BLOCK + EPB * NB;       // last 320 threads do basis
    if (bi >= 0) {
      int e = bi / NB, n = bi - (bi / NB) * NB;
      float d  = dist[e0 + e];
      float xv = d * 0.25f;
      float x2 = xv * xv, x4 = x2 * x2, x5 = x4 * xv;
      float env = 1.0f / xv + x5 * fmaf(xv, fmaf(xv, -21.0f, 48.0f), -28.0f);
      env = (xv < 1.0f) ? env : 0.0f;
      s_basis[e * NB + n] = env * sinf(freq[n] * xv);
    }
  }
  __syncthreads();

  // ---- region B: radial MLP hidden layer (512 tasks) + z for instr 0 ----
  {
    int e = tid >> 4, t = tid & 15;
    float v = b1[t];
    #pragma unroll
    for (int n = 0; n < NB; ++n) v = fmaf(s_basis[e * NB + n], W1[n * NH + t], v);
    v = v / (1.0f + expf(-v));          // silu
    s_hb[e * 32 + t] = f2bf(v);
    s_hb[e * 32 + t + 16] = 0;
  }
  z_phase< 0, 1, 1, 1,   0, 0>(tid, s_xo, s_sh, s_z0);
  __syncthreads();

  short8b hB = *(const short8b*)(s_hb + my_e * 32 + lq * 8);
  __syncthreads();   // protect aliased s_basis/s_hb before z_phase<1> overwrite

  float acc[4][9];
  #pragma unroll
  for (int r = 0; r < 4; ++r)
    #pragma unroll
    for (int a = 0; a < 9; ++a) acc[r][a] = 0.f;

  // ---- pipelined main: z(i+1) || contract(i), one barrier each ----
  z_phase< 1, 1, 3, 3,   0, 1>(tid, s_xo, s_sh, s_z1);
  contract< 0, 1, 0>(ls, lq, a_wt, b_uh, my_e, W2b, b2, s_z0, hB, acc);
  __syncthreads();
  z_phase< 2, 1, 5, 5,   0, 4>(tid, s_xo, s_sh, s_z0);
  contract< 1, 3, 1>(ls, lq, a_wt, b_uh, my_e, W2b, b2, s_z1, hB, acc);
  __syncthreads();
  z_phase< 3, 3, 1, 3,  32, 0>(tid, s_xo, s_sh, s_z1);
  contract< 2, 5, 4>(ls, lq, a_wt, b_uh, my_e, W2b, b2, s_z0, hB, acc);
  __syncthreads();
  z_phase< 4, 3, 3, 1,  32, 1>(tid, s_xo, s_sh, s_z0);
  contract< 3, 3, 1>(ls, lq, a_wt, b_uh, my_e, W2b, b2, s_z1, hB, acc);
  __syncthreads();
  z_phase< 5, 3, 3, 5,  32, 1>(tid, s_xo, s_sh, s_z1);
  contract< 4, 1, 0>(ls, lq, a_wt, b_uh, my_e, W2b, b2, s_z0, hB, acc);
  __syncthreads();
  z_phase< 6, 3, 5, 3,  32, 4>(tid, s_xo, s_sh, s_z0);
  contract< 5, 5, 4>(ls, lq, a_wt, b_uh, my_e, W2b, b2, s_z1, hB, acc);
  __syncthreads();
  z_phase< 7, 5, 1, 5, 128, 0>(tid, s_xo, s_sh, s_z1);
  contract< 6, 3, 1>(ls, lq, a_wt, b_uh, my_e, W2b, b2, s_z0, hB, acc);
  __syncthreads();
  z_phase< 8, 5, 3, 3, 128, 1>(tid, s_xo, s_sh, s_z0);
  contract< 7, 5, 4>(ls, lq, a_wt, b_uh, my_e, W2b, b2, s_z1, hB, acc);
  __syncthreads();
  z_phase< 9, 5, 5, 1, 128, 4>(tid, s_xo, s_sh, s_z1);
  contract< 8, 3, 1>(ls, lq, a_wt, b_uh, my_e, W2b, b2, s_z0, hB, acc);
  __syncthreads();
  z_phase<10, 5, 5, 5, 128, 4>(tid, s_xo, s_sh, s_z0);
  contract< 9, 1, 0>(ls, lq, a_wt, b_uh, my_e, W2b, b2, s_z1, hB, acc);
  __syncthreads();
  contract<10, 5, 4>(ls, lq, a_wt, b_uh, my_e, W2b, b2, s_z0, hB, acc);

  // ---- cross-wave (u-half) reduction into s_xo (x reads all done) ----
  __syncthreads();
  if (b_uh == 1) {
    float* row = s_xo + my_e * XSTR;
    #pragma unroll
    for (int r = 0; r < 4; ++r) {
      int w = a_wt * 16 + lq * 4 + r;
      row[w] = acc[r][0];
      #pragma unroll
      for (int k = 0; k < 3; ++k) row[32 + w * 3 + k] = acc[r][1 + k];
      #pragma unroll
      for (int k = 0; k < 5; ++k) row[128 + w * 5 + k] = acc[r][4 + k];
    }
  }
  __syncthreads();
  if (b_uh == 0) {
    float* row = s_xo + my_e * XSTR;
    #pragma unroll
    for (int r = 0; r < 4; ++r) {
      int w = a_wt * 16 + lq * 4 + r;
      row[w] += acc[r][0];
      #pragma unroll
      for (int k = 0; k < 3; ++k) row[32 + w * 3 + k] += acc[r][1 + k];
      #pragma unroll
      for (int k = 0; k < 5; ++k) row[128 + w * 5 + k] += acc[r][4 + k];
    }
  }
  __syncthreads();
  // coalesced store: 32 rows x 288 = 2304 float4
  for (int i4 = tid; i4 < EPB * 72; i4 += BLOCK) {
    int e = i4 / 72, r = i4 - e * 72;
    float4 v = *(const float4*)(s_xo + e * XSTR + r * 4);
    *(float4*)(out + (size_t)(e0 + e) * DIM_IN + r * 4) = v;
  }
}

// ===================== host-side Wigner-3j (mirrors reference) =====================
typedef std::complex<double> cd;

static double factd(int n) { double r = 1; for (int i = 2; i <= n; ++i) r *= i; return r; }

static double su2_cg(int j1, int j2, int j3, int m1, int m2, int m3) {
  if (m3 != m1 + m2) return 0.0;
  int vmin = std::max(std::max(-j1 + j2 + m3, -j1 + m1), 0);
  int vmax = std::min(std::min(j2 + j3 + m1, j3 - j1 + j2), j3 + m3);
  if (vmax < vmin) return 0.0;
  double c = std::sqrt(
      factd(2*j3+1) * factd(j3+j1-j2) * factd(j3-j1+j2) * factd(j1+j2-j3) / factd(j1+j2+j3+1)
      * factd(j3+m3) * factd(j3-m3)
      / (factd(j1+m1) * factd(j1-m1) * factd(j2+m2) * factd(j2-m2)));
  double s = 0.0;
  for (int v = vmin; v <= vmax; ++v) {
    double sg = ((v + j2 + m2) & 1) ? -1.0 : 1.0;
    s += sg * factd(j2+j3+m1-v) * factd(j1-m1+v)
         / (factd(v) * factd(j3-j1+j2-v) * factd(j3+m3-v) * factd(v+j1-j2-m3));
  }
  return c * s;
}

static void qmat(int l, cd q[5][5]) {
  for (int a = 0; a < 5; ++a) for (int b = 0; b < 5; ++b) q[a][b] = cd(0, 0);
  const double s = 1.0 / std::sqrt(2.0);
  for (int m = -l; m < 0; ++m) {
    q[l + m][l - m] = cd(s, 0);
    q[l + m][l + m] = cd(0, -s);
  }
  q[l][l] = cd(1, 0);
  for (int m = 1; m <= l; ++m) {
    double sg = (m & 1) ? -1.0 : 1.0;
    q[l + m][l + m] = cd(sg * s, 0);
    q[l + m][l - m] = cd(0, sg * s);
  }
  cd ph = (l == 0) ? cd(1, 0) : (l == 1) ? cd(0, -1) : cd(-1, 0);  // (-i)^l
  for (int a = 0; a < 5; ++a) for (int b = 0; b < 5; ++b) q[a][b] *= ph;
}

static void wigner3j(int l1, int l2, int l3, double C[5][5][5]) {
  int d1 = 2*l1+1, d2 = 2*l2+1, d3 = 2*l3+1;
  cd q1[5][5], q2[5][5], q3[5][5];
  qmat(l1, q1); qmat(l2, q2); qmat(l3, q3);
  double norm2 = 0;
  for (int j = 0; j < d1; ++j)
    for (int l = 0; l < d2; ++l)
      for (int n = 0; n < d3; ++n) {
        cd sum(0, 0);
        for (int i = 0; i < d1; ++i)
          for (int k = 0; k < d2; ++k)
            for (int m = 0; m < d3; ++m) {
              double cg = su2_cg(l1, l2, l3, i - l1, k - l2, m - l3);
              if (cg != 0.0) sum += q1[i][j] * q2[k][l] * std::conj(q3[m][n]) * cg;
            }
        C[j][l][n] = sum.real();
        norm2 += C[j][l][n] * C[j][l][n];
      }
  double nrm = std::sqrt(norm2);
  if (nrm > 0)
    for (int j = 0; j < d1; ++j)
      for (int l = 0; l < d2; ++l)
        for (int n = 0; n < d3; ++n) C[j][l][n] /= nrm;
}

static void build_C_host(float C_out[NINSTR][125]) {
  const int L1[NINSTR] = {0,0,0,1,1,1,1,2,2,2,2};
  const int L2[NINSTR] = {0,1,2,0,1,1,2,0,1,2,2};
  const int L3[NINSTR] = {0,1,2,1,0,2,1,2,1,0,2};
  std::memset(C_out, 0, sizeof(float) * NINSTR * 125);
  for (int ins = 0; ins < NINSTR; ++ins) {
    int l1 = L1[ins], l2 = L2[ins], l3 = L3[ins];
    int d1 = 2*l1+1, d2 = 2*l2+1, d3 = 2*l3+1;
    double C[5][5][5];
    wigner3j(l1, l2, l3, C);
    double fan = (l3 == 0) ? 96.0 : 128.0;
    double pw = std::sqrt((2*l3+1) / fan);
    for (int i = 0; i < d1; ++i)
      for (int j = 0; j < d2; ++j)
        for (int k = 0; k < d3; ++k)
          C_out[ins][(i * d2 + j) * d3 + k] = (float)(pw * C[i][j][k]);
  }
}

extern "C" void kernel_launch(void* const* d_in, const int* in_sizes, int n_in,
                              void* d_out, int out_size, void* d_ws, size_t ws_size,
                              hipStream_t stream) {
  static float hC[NINSTR][125];
  build_C_host(hC);
  void* dC = nullptr;
  hipGetSymbolAddress(&dC, HIP_SYMBOL(g_C));
  hipMemcpyAsync(dC, hC, sizeof(hC), hipMemcpyHostToDevice, stream);

  const float* xg   = (const float*)d_in[0];
  const float* shg  = (const float*)d_in[1];
  const float* dist = (const float*)d_in[2];
  const float* freq = (const float*)d_in[3];
  const float* W1   = (const float*)d_in[4];
  const float* b1   = (const float*)d_in[5];
  const float* W2   = (const float*)d_in[6];
  const float* b2   = (const float*)d_in[7];
  float* out = (float*)d_out;
  unsigned short* W2b = (unsigned short*)d_ws;    // 720896 bytes

  prep_w2<<<(W2B_ELEMS + 255) / 256, 256, 0, stream>>>(W2, W2b);

  int E = in_sizes[2];            // 16384
  int blocks = E / EPB;           // 512
  conv_kernel<<<blocks, BLOCK, 0, stream>>>(xg, shg, dist, freq, W1, b1, W2b, b2, out);
}

// Round 8
// 80.585 us; speedup vs baseline: 5.6614x; 1.3614x over previous
//
#include <hip/hip_runtime.h>
#include <cmath>
#include <complex>
#include <cstring>
#include <algorithm>

#define DIM_IN  288
#define DIM_SHD 9
#define NB      10
#define NH      16
#define EPB     16
#define BLOCK   256
#define NINSTR  11
#define XSTR    292
#define ZSTR    164
#define W2B_ELEMS (NINSTR * 32 * 32 * 32)   // [ins][u][w][t0..31]; t=16 holds b2, t>16 zero

// LDS pool layout (floats), total 10112 fl = 40448 B -> 4 blocks/CU:
//   s_xo : [0, 4672)         16*292  x staging; reused for out gather
//   s_z  : [4672, 9920)      2*16*164 z double buffer
//   s_sh : [9920, 10112)     16*12
//   s_basis: alias s_z[1][0..160)             (dead before z_phase<1>)
//   s_hb   : alias s_z[1][160..288) as ushort (dead before z_phase<1>)
#define OFF_XO 0
#define OFF_Z  4672
#define OFF_SH 9920
#define POOLSZ 10112

typedef __attribute__((ext_vector_type(8))) short  short8b;
typedef __attribute__((ext_vector_type(4))) float  f32x4;

__device__ float g_C[NINSTR][125];

__device__ __forceinline__ unsigned short f2bf(float f) {
  unsigned int u = __float_as_uint(f);
  unsigned int r = (u + 0x7fffu + ((u >> 16) & 1u)) >> 16;   // RNE
  return (unsigned short)r;
}

// W2 -> bf16 [ins][u][w][t]; t<16 = W2 row t, t==16 = b2 (hB carries 1.0 there), t>16 = 0
__global__ __launch_bounds__(256) void prep_w2(const float* __restrict__ W2,
                                               const float* __restrict__ b2,
                                               unsigned short* __restrict__ W2b) {
  int gid = blockIdx.x * 256 + threadIdx.x;
  if (gid < W2B_ELEMS) {
    int c = gid >> 5, t = gid & 31;          // c = ins*1024 + u*32 + w
    float v = (t < 16) ? W2[(size_t)t * 11264 + c] : (t == 16 ? b2[c] : 0.0f);
    W2b[gid] = f2bf(v);
  }
}

// ---- z-phase: 16 edges x 32 u over 256 threads, LDS->LDS ----
template<int INS,int D1,int D2,int D3,int OFF1,int OFF2>
__device__ __forceinline__ void z_phase(
    int tid, const float* __restrict__ s_x,
    const float* __restrict__ s_sh, float* __restrict__ zdst)
{
  const float* __restrict__ Cp = g_C[INS];
  #pragma unroll
  for (int s = 0; s < 2; ++s) {
    int id = tid + s * BLOCK;
    int e = id >> 5, u = id & 31;
    const float* xe = s_x + e * XSTR + OFF1 + u * D1;
    float zk[D3];
    #pragma unroll
    for (int k = 0; k < D3; ++k) zk[k] = 0.f;
    #pragma unroll
    for (int i = 0; i < D1; ++i) {
      float xv = xe[i];
      #pragma unroll
      for (int j = 0; j < D2; ++j) {
        float pr = xv * s_sh[e * 12 + OFF2 + j];
        #pragma unroll
        for (int k = 0; k < D3; ++k)
          zk[k] = fmaf(Cp[(i * D2 + j) * D3 + k], pr, zk[k]);
      }
    }
    #pragma unroll
    for (int k = 0; k < D3; ++k) zdst[e * ZSTR + k * 32 + u] = zk[k];
  }
}

// ---- MFMA weight-gen (bias folded via t=16) + u-contraction ----
template<int INS,int D3,int SB>
__device__ __forceinline__ void contract(
    int ls, int lq, int a_wt, int b_uh, int my_e,
    const unsigned short* __restrict__ W2b,
    const float* __restrict__ zbuf, short8b hB, float (&acc)[4][9])
{
  const unsigned short* Ap =
      W2b + ((size_t)(INS * 32 + b_uh * 16) * 32 + a_wt * 16 + ls) * 32 + lq * 8;
  const float* zb = zbuf + my_e * ZSTR + b_uh * 16;
  const f32x4 zero4 = {0.f, 0.f, 0.f, 0.f};

  short8b Ra = *(const short8b*)(Ap);
  f32x4 w_cur = __builtin_amdgcn_mfma_f32_16x16x32_bf16(Ra, hB, zero4, 0, 0, 0);
  short8b Rb = *(const short8b*)(Ap + 1024);

  #pragma unroll
  for (int c = 0; c < 4; ++c) {
    float4 zq[D3];
    #pragma unroll
    for (int k = 0; k < D3; ++k)
      zq[k] = *(const float4*)(zb + k * 32 + c * 4);
    #pragma unroll
    for (int i = 0; i < 4; ++i) {
      const int g = c * 4 + i;              // u index
      f32x4 w_next;
      if (g < 15) {
        w_next = __builtin_amdgcn_mfma_f32_16x16x32_bf16(Rb, hB, zero4, 0, 0, 0);
        if (g + 2 < 16) Rb = *(const short8b*)(Ap + (size_t)(g + 2) * 1024);
      }
      #pragma unroll
      for (int k = 0; k < D3; ++k) {
        const float zz = (i == 0) ? zq[k].x : (i == 1) ? zq[k].y
                       : (i == 2) ? zq[k].z : zq[k].w;
        acc[0][SB + k] = fmaf(w_cur[0], zz, acc[0][SB + k]);
        acc[1][SB + k] = fmaf(w_cur[1], zz, acc[1][SB + k]);
        acc[2][SB + k] = fmaf(w_cur[2], zz, acc[2][SB + k]);
        acc[3][SB + k] = fmaf(w_cur[3], zz, acc[3][SB + k]);
      }
      if (g < 15) w_cur = w_next;
    }
  }
}

// NOTE (journal): empirical on this hipcc, VGPR cap = 256 / (2nd launch_bounds arg):
// arg=2 -> 128 (r4/r5/r7), arg=4 -> 64 (r3/r6, catastrophic spill). Keep arg=2.
__global__ __launch_bounds__(BLOCK, 2) void conv_kernel(
    const float* __restrict__ xg, const float* __restrict__ shg,
    const float* __restrict__ dist, const float* __restrict__ freq,
    const float* __restrict__ W1, const float* __restrict__ b1,
    const unsigned short* __restrict__ W2b,
    float* __restrict__ out)
{
  __shared__ float s_pool[POOLSZ];        // 40448 B
  float* s_xo = s_pool + OFF_XO;
  float* s_z0 = s_pool + OFF_Z;
  float* s_z1 = s_pool + OFF_Z + EPB * ZSTR;
  float* s_sh = s_pool + OFF_SH;
  float* s_basis = s_z1;                                // 160 fl, aliased
  unsigned short* s_hb = (unsigned short*)(s_z1 + 160); // 512 ushort, aliased

  const int tid = threadIdx.x;
  const int e0 = blockIdx.x * EPB;
  const int l  = tid & 63;
  const int ls = l & 15;          // e-col (B/C cols) & w-row selector (A rows)
  const int lq = l >> 4;          // 0..3 k-slice / output reg quad
  const int wid = tid >> 6;       // 0..3
  const int a_wt = wid >> 1;      // w-tile 0/1
  const int b_uh = wid & 1;       // u-half 0/1
  const int my_e = ls;

  // ---- region A: stage x (coalesced), sh, radial basis ----
  for (int i4 = tid; i4 < EPB * 72; i4 += BLOCK) {
    int e = i4 / 72, r = i4 - e * 72;
    *(float4*)(s_xo + e * XSTR + r * 4) =
        *(const float4*)(xg + (size_t)(e0 + e) * DIM_IN + r * 4);
  }
  if (tid < EPB * DIM_SHD) {
    int e = tid / DIM_SHD, c = tid - (tid / DIM_SHD) * DIM_SHD;
    s_sh[e * 12 + c] = shg[(size_t)(e0 + e) * DIM_SHD + c];
  }
  if (tid < EPB * NB) {
    int e = tid / NB, n = tid - (tid / NB) * NB;
    float d  = dist[e0 + e];
    float xv = d * 0.25f;
    float x2 = xv * xv, x4 = x2 * x2, x5 = x4 * xv;
    float env = 1.0f / xv + x5 * fmaf(xv, fmaf(xv, -21.0f, 48.0f), -28.0f);
    env = (xv < 1.0f) ? env : 0.0f;
    s_basis[e * NB + n] = env * sinf(freq[n] * xv);
  }
  __syncthreads();

  // ---- region B: radial MLP hidden layer (256 tasks) + z for instr 0 ----
  {
    int e = tid >> 4, t = tid & 15;
    float v = b1[t];
    #pragma unroll
    for (int n = 0; n < NB; ++n) v = fmaf(s_basis[e * NB + n], W1[n * NH + t], v);
    v = v / (1.0f + expf(-v));          // silu
    s_hb[e * 32 + t] = f2bf(v);
    s_hb[e * 32 + t + 16] = (t == 0) ? (unsigned short)0x3F80 : (unsigned short)0; // 1.0 at t=16 (bias row)
  }
  z_phase< 0, 1, 1, 1,   0, 0>(tid, s_xo, s_sh, s_z0);
  __syncthreads();

  short8b hB = *(const short8b*)(s_hb + my_e * 32 + lq * 8);
  __syncthreads();   // protect aliased s_basis/s_hb before z_phase<1> overwrite

  float acc[4][9];
  #pragma unroll
  for (int r = 0; r < 4; ++r)
    #pragma unroll
    for (int a = 0; a < 9; ++a) acc[r][a] = 0.f;

  // ---- pipelined main: z(i+1) || contract(i), one barrier each ----
  z_phase< 1, 1, 3, 3,   0, 1>(tid, s_xo, s_sh, s_z1);
  contract< 0, 1, 0>(ls, lq, a_wt, b_uh, my_e, W2b, s_z0, hB, acc);
  __syncthreads();
  z_phase< 2, 1, 5, 5,   0, 4>(tid, s_xo, s_sh, s_z0);
  contract< 1, 3, 1>(ls, lq, a_wt, b_uh, my_e, W2b, s_z1, hB, acc);
  __syncthreads();
  z_phase< 3, 3, 1, 3,  32, 0>(tid, s_xo, s_sh, s_z1);
  contract< 2, 5, 4>(ls, lq, a_wt, b_uh, my_e, W2b, s_z0, hB, acc);
  __syncthreads();
  z_phase< 4, 3, 3, 1,  32, 1>(tid, s_xo, s_sh, s_z0);
  contract< 3, 3, 1>(ls, lq, a_wt, b_uh, my_e, W2b, s_z1, hB, acc);
  __syncthreads();
  z_phase< 5, 3, 3, 5,  32, 1>(tid, s_xo, s_sh, s_z1);
  contract< 4, 1, 0>(ls, lq, a_wt, b_uh, my_e, W2b, s_z0, hB, acc);
  __syncthreads();
  z_phase< 6, 3, 5, 3,  32, 4>(tid, s_xo, s_sh, s_z0);
  contract< 5, 5, 4>(ls, lq, a_wt, b_uh, my_e, W2b, s_z1, hB, acc);
  __syncthreads();
  z_phase< 7, 5, 1, 5, 128, 0>(tid, s_xo, s_sh, s_z1);
  contract< 6, 3, 1>(ls, lq, a_wt, b_uh, my_e, W2b, s_z0, hB, acc);
  __syncthreads();
  z_phase< 8, 5, 3, 3, 128, 1>(tid, s_xo, s_sh, s_z0);
  contract< 7, 5, 4>(ls, lq, a_wt, b_uh, my_e, W2b, s_z1, hB, acc);
  __syncthreads();
  z_phase< 9, 5, 5, 1, 128, 4>(tid, s_xo, s_sh, s_z1);
  contract< 8, 3, 1>(ls, lq, a_wt, b_uh, my_e, W2b, s_z0, hB, acc);
  __syncthreads();
  z_phase<10, 5, 5, 5, 128, 4>(tid, s_xo, s_sh, s_z0);
  contract< 9, 1, 0>(ls, lq, a_wt, b_uh, my_e, W2b, s_z1, hB, acc);
  __syncthreads();
  contract<10, 5, 4>(ls, lq, a_wt, b_uh, my_e, W2b, s_z0, hB, acc);

  // ---- cross-wave (u-half) reduction into s_xo (x reads all done) ----
  __syncthreads();
  if (b_uh == 1) {
    float* row = s_xo + my_e * XSTR;
    #pragma unroll
    for (int r = 0; r < 4; ++r) {
      int w = a_wt * 16 + lq * 4 + r;
      row[w] = acc[r][0];
      #pragma unroll
      for (int k = 0; k < 3; ++k) row[32 + w * 3 + k] = acc[r][1 + k];
      #pragma unroll
      for (int k = 0; k < 5; ++k) row[128 + w * 5 + k] = acc[r][4 + k];
    }
  }
  __syncthreads();
  if (b_uh == 0) {
    float* row = s_xo + my_e * XSTR;
    #pragma unroll
    for (int r = 0; r < 4; ++r) {
      int w = a_wt * 16 + lq * 4 + r;
      row[w] += acc[r][0];
      #pragma unroll
      for (int k = 0; k < 3; ++k) row[32 + w * 3 + k] += acc[r][1 + k];
      #pragma unroll
      for (int k = 0; k < 5; ++k) row[128 + w * 5 + k] += acc[r][4 + k];
    }
  }
  __syncthreads();
  // coalesced store: 16 rows x 288 = 1152 float4
  for (int i4 = tid; i4 < EPB * 72; i4 += BLOCK) {
    int e = i4 / 72, r = i4 - e * 72;
    float4 v = *(const float4*)(s_xo + e * XSTR + r * 4);
    *(float4*)(out + (size_t)(e0 + e) * DIM_IN + r * 4) = v;
  }
}

// ===================== host-side Wigner-3j (mirrors reference) =====================
typedef std::complex<double> cd;

static double factd(int n) { double r = 1; for (int i = 2; i <= n; ++i) r *= i; return r; }

static double su2_cg(int j1, int j2, int j3, int m1, int m2, int m3) {
  if (m3 != m1 + m2) return 0.0;
  int vmin = std::max(std::max(-j1 + j2 + m3, -j1 + m1), 0);
  int vmax = std::min(std::min(j2 + j3 + m1, j3 - j1 + j2), j3 + m3);
  if (vmax < vmin) return 0.0;
  double c = std::sqrt(
      factd(2*j3+1) * factd(j3+j1-j2) * factd(j3-j1+j2) * factd(j1+j2-j3) / factd(j1+j2+j3+1)
      * factd(j3+m3) * factd(j3-m3)
      / (factd(j1+m1) * factd(j1-m1) * factd(j2+m2) * factd(j2-m2)));
  double s = 0.0;
  for (int v = vmin; v <= vmax; ++v) {
    double sg = ((v + j2 + m2) & 1) ? -1.0 : 1.0;
    s += sg * factd(j2+j3+m1-v) * factd(j1-m1+v)
         / (factd(v) * factd(j3-j1+j2-v) * factd(j3+m3-v) * factd(v+j1-j2-m3));
  }
  return c * s;
}

static void qmat(int l, cd q[5][5]) {
  for (int a = 0; a < 5; ++a) for (int b = 0; b < 5; ++b) q[a][b] = cd(0, 0);
  const double s = 1.0 / std::sqrt(2.0);
  for (int m = -l; m < 0; ++m) {
    q[l + m][l - m] = cd(s, 0);
    q[l + m][l + m] = cd(0, -s);
  }
  q[l][l] = cd(1, 0);
  for (int m = 1; m <= l; ++m) {
    double sg = (m & 1) ? -1.0 : 1.0;
    q[l + m][l + m] = cd(sg * s, 0);
    q[l + m][l - m] = cd(0, sg * s);
  }
  cd ph = (l == 0) ? cd(1, 0) : (l == 1) ? cd(0, -1) : cd(-1, 0);  // (-i)^l
  for (int a = 0; a < 5; ++a) for (int b = 0; b < 5; ++b) q[a][b] *= ph;
}

static void wigner3j(int l1, int l2, int l3, double C[5][5][5]) {
  int d1 = 2*l1+1, d2 = 2*l2+1, d3 = 2*l3+1;
  cd q1[5][5], q2[5][5], q3[5][5];
  qmat(l1, q1); qmat(l2, q2); qmat(l3, q3);
  double norm2 = 0;
  for (int j = 0; j < d1; ++j)
    for (int l = 0; l < d2; ++l)
      for (int n = 0; n < d3; ++n) {
        cd sum(0, 0);
        for (int i = 0; i < d1; ++i)
          for (int k = 0; k < d2; ++k)
            for (int m = 0; m < d3; ++m) {
              double cg = su2_cg(l1, l2, l3, i - l1, k - l2, m - l3);
              if (cg != 0.0) sum += q1[i][j] * q2[k][l] * std::conj(q3[m][n]) * cg;
            }
        C[j][l][n] = sum.real();
        norm2 += C[j][l][n] * C[j][l][n];
      }
  double nrm = std::sqrt(norm2);
  if (nrm > 0)
    for (int j = 0; j < d1; ++j)
      for (int l = 0; l < d2; ++l)
        for (int n = 0; n < d3; ++n) C[j][l][n] /= nrm;
}

static void build_C_host(float C_out[NINSTR][125]) {
  const int L1[NINSTR] = {0,0,0,1,1,1,1,2,2,2,2};
  const int L2[NINSTR] = {0,1,2,0,1,1,2,0,1,2,2};
  const int L3[NINSTR] = {0,1,2,1,0,2,1,2,1,0,2};
  std::memset(C_out, 0, sizeof(float) * NINSTR * 125);
  for (int ins = 0; ins < NINSTR; ++ins) {
    int l1 = L1[ins], l2 = L2[ins], l3 = L3[ins];
    int d1 = 2*l1+1, d2 = 2*l2+1, d3 = 2*l3+1;
    double C[5][5][5];
    wigner3j(l1, l2, l3, C);
    double fan = (l3 == 0) ? 96.0 : 128.0;
    double pw = std::sqrt((2*l3+1) / fan);
    for (int i = 0; i < d1; ++i)
      for (int j = 0; j < d2; ++j)
        for (int k = 0; k < d3; ++k)
          C_out[ins][(i * d2 + j) * d3 + k] = (float)(pw * C[i][j][k]);
  }
}

extern "C" void kernel_launch(void* const* d_in, const int* in_sizes, int n_in,
                              void* d_out, int out_size, void* d_ws, size_t ws_size,
                              hipStream_t stream) {
  static float hC[NINSTR][125];
  build_C_host(hC);
  void* dC = nullptr;
  hipGetSymbolAddress(&dC, HIP_SYMBOL(g_C));
  hipMemcpyAsync(dC, hC, sizeof(hC), hipMemcpyHostToDevice, stream);

  const float* xg   = (const float*)d_in[0];
  const float* shg  = (const float*)d_in[1];
  const float* dist = (const float*)d_in[2];
  const float* freq = (const float*)d_in[3];
  const float* W1   = (const float*)d_in[4];
  const float* b1   = (const float*)d_in[5];
  const float* W2   = (const float*)d_in[6];
  const float* b2   = (const float*)d_in[7];
  float* out = (float*)d_out;
  unsigned short* W2b = (unsigned short*)d_ws;    // 720896 bytes

  prep_w2<<<(W2B_ELEMS + 255) / 256, 256, 0, stream>>>(W2, b2, W2b);

  int E = in_sizes[2];            // 16384
  int blocks = E / EPB;           // 1024
  conv_kernel<<<blocks, BLOCK, 0, stream>>>(xg, shg, dist, freq, W1, b1, W2b, out);
}